// Round 1
// baseline (4204.914 us; speedup 1.0000x reference)
//
#include <hip/hip_runtime.h>
#include <stdint.h>

typedef __bf16 bf16x8 __attribute__((ext_vector_type(8)));
typedef float f32x4 __attribute__((ext_vector_type(4)));
typedef unsigned long long ull_t;

#define DEV __device__ __forceinline__

DEV unsigned short f2bf(float f) {
  unsigned int u = __float_as_uint(f);
  return (unsigned short)((u + 0x7FFFu + ((u >> 16) & 1u)) >> 16);  // RNE
}

DEV f32x4 zero4() { f32x4 z = {0.f, 0.f, 0.f, 0.f}; return z; }

DEV float softplusf(float v) { return (v > 15.f) ? v : log1pf(expf(v)); }

// A/B fragment for v_mfma_f32_16x16x32_bf16, split-4 k-layout:
//   element j (0..7) of lane l -> k = 16*(j>>2) + 4*(l>>4) + (j&3)
// p points at (row, k = kt*32 + 4*(l>>4)); two 8B chunks 16 elements apart.
DEV bf16x8 load_frag_split(const unsigned short* p) {
  union { bf16x8 v; ull_t q[2]; } u;
  u.q[0] = *(const ull_t*)(p);
  u.q[1] = *(const ull_t*)(p + 16);
  return u.v;
}

// Pack W[K][Ncols] (f32 row-major) -> fragment-major bf16:
// P[((kt*NT + nt)*64 + lane)*8 + j] = W[kt*32 + 16*(j>>2) + 4*(lane>>4) + (j&3)][nt*16 + (lane&15)]
__global__ void pack_weight(const float* __restrict__ W, unsigned short* __restrict__ P,
                            int K, int Ncols) {
  int idx = blockIdx.x * 256 + threadIdx.x;
  if (idx >= K * Ncols) return;
  int j = idx & 7;
  int lane = (idx >> 3) & 63;
  int rest = idx >> 9;
  int NT = Ncols >> 4;
  int nt = rest % NT;
  int kt = rest / NT;
  int k = kt * 32 + ((j >> 2) * 16) + ((lane >> 4) * 4) + (j & 3);
  int col = nt * 16 + (lane & 15);
  P[idx] = f2bf(W[(size_t)k * Ncols + col]);
}

__global__ void k_deg(const int* __restrict__ dst, float* __restrict__ deg, int E) {
  int i = blockIdx.x * 256 + threadIdx.x;
  if (i < E) atomicAdd(&deg[dst[i]], 1.0f);
}

__global__ void k_dis(const float* __restrict__ deg, float* __restrict__ dis, int n) {
  int i = blockIdx.x * 256 + threadIdx.x;
  if (i < n) dis[i] = rsqrtf(deg[i] + 1.0f);
}

// acc[dst] += feat[src] * dis[src]*dis[dst]; one thread per (edge, 4-channel chunk)
__global__ void k_gather_scale_add(const float* __restrict__ feat,
                                   const int* __restrict__ srcs, const int* __restrict__ dsts,
                                   const float* __restrict__ dis,
                                   float* __restrict__ acc, int E, int C4, int cols) {
  int idx = blockIdx.x * 256 + threadIdx.x;
  if (idx >= E * C4) return;
  int e = idx / C4;
  int q = (idx - e * C4) * 4;
  int s = srcs[e], d = dsts[e];
  float c = dis[s] * dis[d];
  float4 v = *(const float4*)&feat[(size_t)s * cols + q];
  float* a = &acc[(size_t)d * cols + q];
  atomicAdd(a + 0, v.x * c);
  atomicAdd(a + 1, v.y * c);
  atomicAdd(a + 2, v.z * c);
  atomicAdd(a + 3, v.w * c);
}

// acc = relu(acc + hw*dis^2 + bias[col])   (in place)
__global__ void k_finalize(float* __restrict__ acc, const float* __restrict__ hw,
                           const float* __restrict__ dis, const float* __restrict__ bias,
                           int n, int cols) {
  int idx = blockIdx.x * 256 + threadIdx.x;
  if (idx >= n * cols) return;
  int node = idx / cols;
  int c = idx - node * cols;
  float d = dis[node];
  acc[idx] = fmaxf(acc[idx] + hw[idx] * d * d + bias[c], 0.f);
}

// Generic node GEMM: out[r, :NOUT] = inA[r,:K] (+ inB[r,:K]*dis[r]^2) @ Wp (+bias, relu)
// 64-row tile, 4 waves, bf16 MFMA 16x16x32. LDS XOR-swizzled on 8B chunks (no pad).
template <int K, int NOUT, bool COMPOSE, bool RELUBIAS>
__global__ __launch_bounds__(256, 2) void gcn_gemm(
    const float* __restrict__ inA, const float* __restrict__ inB,
    const float* __restrict__ dis,
    const unsigned short* __restrict__ Wp, const float* __restrict__ bias,
    float* __restrict__ out, int out_stride, int nrows) {
  constexpr int NT = NOUT / 16;   // total 16-col tiles
  constexpr int NTW = NOUT / 64;  // n-tiles per wave
  __shared__ unsigned short s_in[64 * K];
  const int tid = threadIdx.x;
  const int r0 = blockIdx.x * 64;

  constexpr int C4R = K / 4;  // 8B chunks per row
  for (int idx = tid; idx < 64 * C4R; idx += 256) {
    int row = idx / C4R;
    int rem = idx - row * C4R;
    int grow = r0 + row;
    float4 v = make_float4(0.f, 0.f, 0.f, 0.f);
    if (grow < nrows) {
      v = *(const float4*)&inA[(size_t)grow * K + rem * 4];
      if constexpr (COMPOSE) {
        float d = dis[grow];
        d *= d;
        float4 w2 = *(const float4*)&inB[(size_t)grow * K + rem * 4];
        v.x += w2.x * d; v.y += w2.y * d; v.z += w2.z * d; v.w += w2.w * d;
      }
    }
    ushort4 b;
    b.x = f2bf(v.x); b.y = f2bf(v.y); b.z = f2bf(v.z); b.w = f2bf(v.w);
    *(ushort4*)&s_in[row * K + ((rem ^ (row & 7)) * 4)] = b;
  }
  __syncthreads();

  const int lane = tid & 63, wid = tid >> 6;
  const int lr = lane & 15, lg = lane >> 4;
  f32x4 acc[4][NTW];
#pragma unroll
  for (int m = 0; m < 4; ++m)
#pragma unroll
    for (int n2 = 0; n2 < NTW; ++n2) acc[m][n2] = zero4();

#pragma unroll
  for (int kt = 0; kt < K / 32; ++kt) {
    bf16x8 a[4];
#pragma unroll
    for (int m = 0; m < 4; ++m) {
      int rA = m * 16 + lr;
      int c1 = (kt * 8 + lg) ^ (rA & 7);
      int c2 = (kt * 8 + lg + 4) ^ (rA & 7);
      union { bf16x8 v; ull_t q[2]; } u;
      u.q[0] = *(const ull_t*)&s_in[rA * K + c1 * 4];
      u.q[1] = *(const ull_t*)&s_in[rA * K + c2 * 4];
      a[m] = u.v;
    }
#pragma unroll
    for (int n2 = 0; n2 < NTW; ++n2) {
      int nt = wid * NTW + n2;
      bf16x8 b = *(const bf16x8*)&Wp[(((size_t)kt * NT + nt) * 64 + lane) * 8];
#pragma unroll
      for (int m = 0; m < 4; ++m)
        acc[m][n2] = __builtin_amdgcn_mfma_f32_16x16x32_bf16(a[m], b, acc[m][n2], 0, 0, 0);
    }
  }

#pragma unroll
  for (int n2 = 0; n2 < NTW; ++n2) {
    int col = (wid * NTW + n2) * 16 + lr;
    float bv = 0.f;
    if (RELUBIAS) bv = bias[col];
#pragma unroll
    for (int m = 0; m < 4; ++m) {
#pragma unroll
      for (int r = 0; r < 4; ++r) {
        int grow = r0 + m * 16 + lg * 4 + r;
        if (grow < nrows) {
          float v = acc[m][n2][r];
          if (RELUBIAS) v = fmaxf(v + bv, 0.f);
          out[(size_t)grow * out_stride + col] = v;
        }
      }
    }
  }
}

// Fused EdgeConv: per 64-edge tile, m = relu([x_dst|x_src|ea] @ W1 + b1) @ W2 + b2,
// then atomicMax into h2[dst, 256+col] (init 0 == fused isfinite-fixup + relu).
__global__ __launch_bounds__(256, 2) void k_edgeconv(
    const float* __restrict__ x, const float* __restrict__ ea,
    const int* __restrict__ srcs, const int* __restrict__ dsts,
    const unsigned short* __restrict__ W1p, const float* __restrict__ b1,
    const unsigned short* __restrict__ W2p, const float* __restrict__ b2,
    float* __restrict__ h2, int E) {
  constexpr int KP1 = 200;  // 192 + 8 pad
  constexpr int KP2 = 264;  // 256 + 8 pad
  __shared__ unsigned short s_in[64 * KP1];
  __shared__ unsigned short s_hid[64 * KP2];
  __shared__ int s_src[64], s_dst[64];
  const int tid = threadIdx.x;
  const int e0 = blockIdx.x * 64;
  if (tid < 64) {
    int e = e0 + tid;
    s_src[tid] = (e < E) ? srcs[e] : 0;
    s_dst[tid] = (e < E) ? dsts[e] : 0;
  }
  __syncthreads();
#pragma unroll
  for (int seg = 0; seg < 3; ++seg) {
#pragma unroll
    for (int it = 0; it < 4; ++it) {
      int idx = it * 256 + tid;
      int ei = idx >> 4;
      int c4 = (idx & 15) * 4;
      const float* row;
      if (seg == 0) row = x + (size_t)s_dst[ei] * 64;
      else if (seg == 1) row = x + (size_t)s_src[ei] * 64;
      else row = ea + (size_t)(e0 + ei) * 64;
      float4 v = make_float4(0.f, 0.f, 0.f, 0.f);
      if (seg != 2 || e0 + ei < E) v = *(const float4*)(row + c4);
      ushort4 b;
      b.x = f2bf(v.x); b.y = f2bf(v.y); b.z = f2bf(v.z); b.w = f2bf(v.w);
      *(ushort4*)&s_in[ei * KP1 + seg * 64 + c4] = b;
    }
  }
  __syncthreads();

  const int lane = tid & 63, wid = tid >> 6;
  const int lr = lane & 15, lg = lane >> 4;
  f32x4 acc[4][4];
#pragma unroll
  for (int m = 0; m < 4; ++m)
#pragma unroll
    for (int n2 = 0; n2 < 4; ++n2) acc[m][n2] = zero4();

  // GEMM1: K=192 -> hidden 256
#pragma unroll
  for (int kt = 0; kt < 6; ++kt) {
    bf16x8 a[4];
#pragma unroll
    for (int m = 0; m < 4; ++m)
      a[m] = load_frag_split(&s_in[(m * 16 + lr) * KP1 + kt * 32 + lg * 4]);
#pragma unroll
    for (int n2 = 0; n2 < 4; ++n2) {
      int nt = wid * 4 + n2;
      bf16x8 b = *(const bf16x8*)&W1p[(((size_t)kt * 16 + nt) * 64 + lane) * 8];
#pragma unroll
      for (int m = 0; m < 4; ++m)
        acc[m][n2] = __builtin_amdgcn_mfma_f32_16x16x32_bf16(a[m], b, acc[m][n2], 0, 0, 0);
    }
  }
#pragma unroll
  for (int n2 = 0; n2 < 4; ++n2) {
    int col = (wid * 4 + n2) * 16 + lr;
    float bv = b1[col];
#pragma unroll
    for (int m = 0; m < 4; ++m)
#pragma unroll
      for (int r = 0; r < 4; ++r) {
        float v = fmaxf(acc[m][n2][r] + bv, 0.f);
        s_hid[(m * 16 + lg * 4 + r) * KP2 + col] = f2bf(v);
      }
  }
  __syncthreads();

  // GEMM2: K=256 -> out 256, scatter atomicMax
#pragma unroll
  for (int m = 0; m < 4; ++m)
#pragma unroll
    for (int n2 = 0; n2 < 4; ++n2) acc[m][n2] = zero4();
#pragma unroll
  for (int kt = 0; kt < 8; ++kt) {
    bf16x8 a[4];
#pragma unroll
    for (int m = 0; m < 4; ++m)
      a[m] = load_frag_split(&s_hid[(m * 16 + lr) * KP2 + kt * 32 + lg * 4]);
#pragma unroll
    for (int n2 = 0; n2 < 4; ++n2) {
      int nt = wid * 4 + n2;
      bf16x8 b = *(const bf16x8*)&W2p[(((size_t)kt * 16 + nt) * 64 + lane) * 8];
#pragma unroll
      for (int m = 0; m < 4; ++m)
        acc[m][n2] = __builtin_amdgcn_mfma_f32_16x16x32_bf16(a[m], b, acc[m][n2], 0, 0, 0);
    }
  }
#pragma unroll
  for (int n2 = 0; n2 < 4; ++n2) {
    int col = (wid * 4 + n2) * 16 + lr;
    float bv = b2[col];
#pragma unroll
    for (int m = 0; m < 4; ++m)
#pragma unroll
      for (int r = 0; r < 4; ++r) {
        int row = m * 16 + lg * 4 + r;
        if (e0 + row < E) {
          float v = acc[m][n2][r] + bv;
          if (v > 0.f)
            atomicMax((int*)&h2[(size_t)s_dst[row] * 512 + 256 + col], __float_as_int(v));
        }
      }
  }
}

// Head MLP: wave-per-node, weights (except W2) staged in LDS.
__global__ __launch_bounds__(256) void k_head(
    const float* __restrict__ x, const float* __restrict__ out3,
    const float* __restrict__ W1, const float* __restrict__ b1,
    const float* __restrict__ W2, const float* __restrict__ b2,
    const float* __restrict__ W3, const float* __restrict__ b3,
    const float* __restrict__ W4, const float* __restrict__ b4,
    float* __restrict__ out, int n) {
  __shared__ float sW1[128 * 64];
  __shared__ float sW3[128 * 32];
  __shared__ float sW4[32 * 2];
  __shared__ float sb1[64], sb2[128], sb3[32], sb4[2];
  __shared__ float sbuf[4][352];
  const int tid = threadIdx.x;
  for (int i = tid; i < 128 * 64; i += 256) sW1[i] = W1[i];
  for (int i = tid; i < 128 * 32; i += 256) sW3[i] = W3[i];
  if (tid < 64) sW4[tid] = W4[tid];
  if (tid < 64) sb1[tid] = b1[tid];
  if (tid < 128) sb2[tid] = b2[tid];
  if (tid < 32) sb3[tid] = b3[tid];
  if (tid < 2) sb4[tid] = b4[tid];
  __syncthreads();
  const int wid = tid >> 6, lane = tid & 63;
  float* B = sbuf[wid];
  const int per = gridDim.x * 4;
  const int iters = (n + per - 1) / per;
  for (int it = 0; it < iters; ++it) {
    const int node = it * per + blockIdx.x * 4 + wid;
    const bool act = node < n;
    if (act) {
      B[lane] = x[(size_t)node * 64 + lane];
      B[64 + lane] = out3[(size_t)node * 64 + lane];
    }
    __syncthreads();
    if (act) {
      float o = sb1[lane];
#pragma unroll 8
      for (int k = 0; k < 128; ++k) o += B[k] * sW1[k * 64 + lane];
      B[128 + lane] = softplusf(o);
    }
    __syncthreads();
    if (act) {
      float o0 = sb2[lane], o1 = sb2[64 + lane];
#pragma unroll 8
      for (int k = 0; k < 64; ++k) {
        float v = B[128 + k];
        o0 += v * W2[k * 128 + lane];
        o1 += v * W2[k * 128 + 64 + lane];
      }
      B[192 + lane] = softplusf(o0);
      B[256 + lane] = softplusf(o1);
    }
    __syncthreads();
    if (act && lane < 32) {
      float o = sb3[lane];
#pragma unroll 8
      for (int k = 0; k < 128; ++k) o += B[192 + k] * sW3[k * 32 + lane];
      B[320 + lane] = softplusf(o);
    }
    __syncthreads();
    if (act && lane < 2) {
      float o = sb4[lane];
#pragma unroll
      for (int k = 0; k < 32; ++k) o += B[320 + k] * sW4[k * 2 + lane];
      out[(size_t)lane * n + node] = o;
    }
    __syncthreads();
  }
}

static inline size_t alignup(size_t v) { return (v + 255) & ~(size_t)255; }

extern "C" void kernel_launch(void* const* d_in, const int* in_sizes, int n_in,
                              void* d_out, int out_size, void* d_ws, size_t ws_size,
                              hipStream_t stream) {
  const float* x = (const float*)d_in[0];
  const int* ei = (const int*)d_in[1];
  const float* ea = (const float*)d_in[2];
  const float* c1W = (const float*)d_in[3];
  const float* c1b = (const float*)d_in[4];
  const float* eW1 = (const float*)d_in[5];
  const float* eb1 = (const float*)d_in[6];
  const float* eW2 = (const float*)d_in[7];
  const float* eb2 = (const float*)d_in[8];
  const float* c2W = (const float*)d_in[9];
  const float* c2b = (const float*)d_in[10];
  const float* c3W = (const float*)d_in[11];
  const float* c3b = (const float*)d_in[12];
  const float* l1W = (const float*)d_in[13];
  const float* l1b = (const float*)d_in[14];
  const float* l2W = (const float*)d_in[15];
  const float* l2b = (const float*)d_in[16];
  const float* l3W = (const float*)d_in[17];
  const float* l3b = (const float*)d_in[18];
  const float* l4W = (const float*)d_in[19];
  const float* l4b = (const float*)d_in[20];
  const int n = in_sizes[0] / 64;
  const int E = in_sizes[1] / 2;
  const int* srcs = ei;
  const int* dsts = ei + E;

  char* w = (char*)d_ws;
  auto alloc = [&](size_t bytes) {
    char* p = w;
    w += alignup(bytes);
    return p;
  };
  float* dis = (float*)alloc((size_t)n * 4);
  float* deg = (float*)alloc((size_t)n * 4);
  float* agg1 = (float*)alloc((size_t)n * 64 * 4);
  float* h2 = (float*)alloc((size_t)n * 512 * 4);  // [out1 | out_e1]
  float* hw2 = (float*)alloc((size_t)n * 256 * 4);
  float* out2 = (float*)alloc((size_t)n * 256 * 4);
  float* hw3 = (float*)alloc((size_t)n * 64 * 4);
  float* out3 = (float*)alloc((size_t)n * 64 * 4);
  unsigned short* p_c1 = (unsigned short*)alloc(64 * 256 * 2);
  unsigned short* p_e1 = (unsigned short*)alloc(192 * 256 * 2);
  unsigned short* p_e2 = (unsigned short*)alloc(256 * 256 * 2);
  unsigned short* p_c2 = (unsigned short*)alloc(512 * 256 * 2);
  unsigned short* p_c3 = (unsigned short*)alloc(256 * 64 * 2);

  hipMemsetAsync(deg, 0, (size_t)n * 4, stream);
  hipMemsetAsync(agg1, 0, (size_t)n * 64 * 4, stream);
  hipMemsetAsync(h2, 0, (size_t)n * 512 * 4, stream);
  hipMemsetAsync(out2, 0, (size_t)n * 256 * 4, stream);
  hipMemsetAsync(out3, 0, (size_t)n * 64 * 4, stream);

  pack_weight<<<(64 * 256) / 256, 256, 0, stream>>>(c1W, p_c1, 64, 256);
  pack_weight<<<(192 * 256) / 256, 256, 0, stream>>>(eW1, p_e1, 192, 256);
  pack_weight<<<(256 * 256) / 256, 256, 0, stream>>>(eW2, p_e2, 256, 256);
  pack_weight<<<(512 * 256) / 256, 256, 0, stream>>>(c2W, p_c2, 512, 256);
  pack_weight<<<(256 * 64) / 256, 256, 0, stream>>>(c3W, p_c3, 256, 64);

  k_deg<<<(E + 255) / 256, 256, 0, stream>>>(dsts, deg, E);
  k_dis<<<(n + 255) / 256, 256, 0, stream>>>(deg, dis, n);

  // conv1: aggregate x (64 ch) before matmul
  k_gather_scale_add<<<(E * 16 + 255) / 256, 256, 0, stream>>>(x, srcs, dsts, dis, agg1, E, 16, 64);
  const int gblocks = (n + 63) / 64;
  gcn_gemm<64, 256, true, true><<<gblocks, 256, 0, stream>>>(agg1, x, dis, p_c1, c1b, h2, 512, n);

  // EdgeConv -> h2[:, 256:512]
  k_edgeconv<<<(E + 63) / 64, 256, 0, stream>>>(x, ea, srcs, dsts, p_e1, eb1, p_e2, eb2, h2, E);

  // conv2: matmul then aggregate (256 ch)
  gcn_gemm<512, 256, false, false><<<gblocks, 256, 0, stream>>>(h2, nullptr, nullptr, p_c2, nullptr, hw2, 256, n);
  k_gather_scale_add<<<(E * 64 + 255) / 256, 256, 0, stream>>>(hw2, srcs, dsts, dis, out2, E, 64, 256);
  k_finalize<<<(n * 256 + 255) / 256, 256, 0, stream>>>(out2, hw2, dis, c2b, n, 256);

  // conv3: matmul then aggregate (64 ch)
  gcn_gemm<256, 64, false, false><<<gblocks, 256, 0, stream>>>(out2, nullptr, nullptr, p_c3, nullptr, hw3, 64, n);
  k_gather_scale_add<<<(E * 16 + 255) / 256, 256, 0, stream>>>(hw3, srcs, dsts, dis, out3, E, 16, 64);
  k_finalize<<<(n * 64 + 255) / 256, 256, 0, stream>>>(out3, hw3, dis, c3b, n, 64);

  k_head<<<320, 256, 0, stream>>>(x, out3, l1W, l1b, l2W, l2b, l3W, l3b, l4W, l4b,
                                  (float*)d_out, n);
}

// Round 2
// 834.097 us; speedup vs baseline: 5.0413x; 5.0413x over previous
//
#include <hip/hip_runtime.h>
#include <stdint.h>

typedef __bf16 bf16x8 __attribute__((ext_vector_type(8)));
typedef float f32x4 __attribute__((ext_vector_type(4)));
typedef unsigned long long ull_t;

#define DEV __device__ __forceinline__

DEV unsigned short f2bf(float f) {
  unsigned int u = __float_as_uint(f);
  return (unsigned short)((u + 0x7FFFu + ((u >> 16) & 1u)) >> 16);  // RNE
}

DEV float bf2f(unsigned short b) { return __uint_as_float((unsigned int)b << 16); }

DEV f32x4 zero4() { f32x4 z = {0.f, 0.f, 0.f, 0.f}; return z; }

DEV float softplusf(float v) { return (v > 15.f) ? v : log1pf(expf(v)); }

// A/B fragment for v_mfma_f32_16x16x32_bf16, split-4 k-layout:
//   element j (0..7) of lane l -> k = 16*(j>>2) + 4*(l>>4) + (j&3)
DEV bf16x8 load_frag_split(const unsigned short* p) {
  union { bf16x8 v; ull_t q[2]; } u;
  u.q[0] = *(const ull_t*)(p);
  u.q[1] = *(const ull_t*)(p + 16);
  return u.v;
}

// Pack W[K][Ncols] (f32 row-major) -> fragment-major bf16.
__global__ void pack_weight(const float* __restrict__ W, unsigned short* __restrict__ P,
                            int K, int Ncols) {
  int idx = blockIdx.x * 256 + threadIdx.x;
  if (idx >= K * Ncols) return;
  int j = idx & 7;
  int lane = (idx >> 3) & 63;
  int rest = idx >> 9;
  int NT = Ncols >> 4;
  int nt = rest % NT;
  int kt = rest / NT;
  int k = kt * 32 + ((j >> 2) * 16) + ((lane >> 4) * 4) + (j & 3);
  int col = nt * 16 + (lane & 15);
  P[idx] = f2bf(W[(size_t)k * Ncols + col]);
}

__global__ void k_deg(const int* __restrict__ dst, int* __restrict__ degi, int E) {
  int i = blockIdx.x * 256 + threadIdx.x;
  if (i < E) atomicAdd(&degi[dst[i]], 1);
}

__global__ void k_dis(const int* __restrict__ degi, float* __restrict__ dis, int n) {
  int i = blockIdx.x * 256 + threadIdx.x;
  if (i < n) dis[i] = rsqrtf((float)degi[i] + 1.0f);
}

// Single-block exclusive scan: ptr[0..n] from degi[0..n-1].
__global__ __launch_bounds__(1024) void k_scan(const int* __restrict__ degi,
                                               int* __restrict__ ptr, int n) {
  __shared__ int part[1024];
  const int tid = threadIdx.x;
  const int chunk = (n + 1023) / 1024;
  const int b = tid * chunk;
  const int e2 = min(n, b + chunk);
  int s = 0;
  for (int i = b; i < e2; ++i) s += degi[i];
  part[tid] = s;
  __syncthreads();
  for (int off = 1; off < 1024; off <<= 1) {
    int val = (tid >= off) ? part[tid - off] : 0;
    __syncthreads();
    part[tid] += val;
    __syncthreads();
  }
  int run = (tid == 0) ? 0 : part[tid - 1];
  for (int i = b; i < e2; ++i) {
    ptr[i] = run;
    run += degi[i];
  }
  if (tid == 1023) ptr[n] = run;
}

// Counting-sort fill: edges grouped by dst.
__global__ void k_fill(const int* __restrict__ srcs, const int* __restrict__ dsts,
                       const int* __restrict__ ptr, int* __restrict__ fillc,
                       int* __restrict__ src_s, int* __restrict__ dst_s,
                       int* __restrict__ perm_s, int E) {
  int e = blockIdx.x * 256 + threadIdx.x;
  if (e >= E) return;
  int d = dsts[e];
  int pos = ptr[d] + atomicAdd(&fillc[d], 1);
  src_s[pos] = srcs[e];
  dst_s[pos] = d;
  perm_s[pos] = e;
}

// Per-node CSR gather: acc = sum_{e in N(v)} feat[src_e]*dis[src]*dis[v].
// FINALIZE: out = relu(acc + hw[v]*dis[v]^2 + bias)  (fused finalize)
template <int COLS, bool FINALIZE>
__global__ __launch_bounds__(256) void k_gather_agg(
    const float* __restrict__ feat, const int* __restrict__ src_s,
    const int* __restrict__ ptr, const float* __restrict__ dis,
    const float* __restrict__ hw, const float* __restrict__ bias,
    float* __restrict__ out, int n) {
  constexpr int V = COLS / 64;
  const int v = blockIdx.x * 4 + (threadIdx.x >> 6);
  if (v >= n) return;
  const int lane = threadIdx.x & 63;
  const int beg = ptr[v], end = ptr[v + 1];
  const float dv = dis[v];
  float acc[V];
#pragma unroll
  for (int i = 0; i < V; ++i) acc[i] = 0.f;
  for (int e = beg; e < end; ++e) {
    int s = src_s[e];
    float c = dis[s] * dv;
    const float* row = feat + (size_t)s * COLS + lane * V;
    if constexpr (V == 4) {
      float4 f = *(const float4*)row;
      acc[0] += f.x * c; acc[1] += f.y * c; acc[2] += f.z * c; acc[3] += f.w * c;
    } else {
      acc[0] += row[0] * c;
    }
  }
  float* op = out + (size_t)v * COLS + lane * V;
  if constexpr (FINALIZE) {
    float d2 = dv * dv;
    const float* hp = hw + (size_t)v * COLS + lane * V;
#pragma unroll
    for (int i = 0; i < V; ++i)
      acc[i] = fmaxf(acc[i] + hp[i] * d2 + bias[lane * V + i], 0.f);
  }
  if constexpr (V == 4) {
    *(float4*)op = make_float4(acc[0], acc[1], acc[2], acc[3]);
  } else {
    op[0] = acc[0];
  }
}

// Generic node GEMM: out[r, :NOUT] = inA[r,:K] (+ inB[r,:K]*dis[r]^2) @ Wp (+bias, relu)
template <int K, int NOUT, bool COMPOSE, bool RELUBIAS>
__global__ __launch_bounds__(256, 2) void gcn_gemm(
    const float* __restrict__ inA, const float* __restrict__ inB,
    const float* __restrict__ dis,
    const unsigned short* __restrict__ Wp, const float* __restrict__ bias,
    float* __restrict__ out, int out_stride, int nrows) {
  constexpr int NT = NOUT / 16;
  constexpr int NTW = NOUT / 64;
  __shared__ unsigned short s_in[64 * K];
  const int tid = threadIdx.x;
  const int r0 = blockIdx.x * 64;

  constexpr int C4R = K / 4;
  for (int idx = tid; idx < 64 * C4R; idx += 256) {
    int row = idx / C4R;
    int rem = idx - row * C4R;
    int grow = r0 + row;
    float4 v = make_float4(0.f, 0.f, 0.f, 0.f);
    if (grow < nrows) {
      v = *(const float4*)&inA[(size_t)grow * K + rem * 4];
      if constexpr (COMPOSE) {
        float d = dis[grow];
        d *= d;
        float4 w2 = *(const float4*)&inB[(size_t)grow * K + rem * 4];
        v.x += w2.x * d; v.y += w2.y * d; v.z += w2.z * d; v.w += w2.w * d;
      }
    }
    ushort4 b;
    b.x = f2bf(v.x); b.y = f2bf(v.y); b.z = f2bf(v.z); b.w = f2bf(v.w);
    *(ushort4*)&s_in[row * K + ((rem ^ (row & 7)) * 4)] = b;
  }
  __syncthreads();

  const int lane = tid & 63, wid = tid >> 6;
  const int lr = lane & 15, lg = lane >> 4;
  f32x4 acc[4][NTW];
#pragma unroll
  for (int m = 0; m < 4; ++m)
#pragma unroll
    for (int n2 = 0; n2 < NTW; ++n2) acc[m][n2] = zero4();

#pragma unroll
  for (int kt = 0; kt < K / 32; ++kt) {
    bf16x8 a[4];
#pragma unroll
    for (int m = 0; m < 4; ++m) {
      int rA = m * 16 + lr;
      int c1 = (kt * 8 + lg) ^ (rA & 7);
      int c2 = (kt * 8 + lg + 4) ^ (rA & 7);
      union { bf16x8 v; ull_t q[2]; } u;
      u.q[0] = *(const ull_t*)&s_in[rA * K + c1 * 4];
      u.q[1] = *(const ull_t*)&s_in[rA * K + c2 * 4];
      a[m] = u.v;
    }
#pragma unroll
    for (int n2 = 0; n2 < NTW; ++n2) {
      int nt = wid * NTW + n2;
      bf16x8 b = *(const bf16x8*)&Wp[(((size_t)kt * NT + nt) * 64 + lane) * 8];
#pragma unroll
      for (int m = 0; m < 4; ++m)
        acc[m][n2] = __builtin_amdgcn_mfma_f32_16x16x32_bf16(a[m], b, acc[m][n2], 0, 0, 0);
    }
  }

#pragma unroll
  for (int n2 = 0; n2 < NTW; ++n2) {
    int col = (wid * NTW + n2) * 16 + lr;
    float bv = 0.f;
    if (RELUBIAS) bv = bias[col];
#pragma unroll
    for (int m = 0; m < 4; ++m) {
#pragma unroll
      for (int r = 0; r < 4; ++r) {
        int grow = r0 + m * 16 + lg * 4 + r;
        if (grow < nrows) {
          float v = acc[m][n2][r];
          if (RELUBIAS) v = fmaxf(v + bv, 0.f);
          out[(size_t)grow * out_stride + col] = v;
        }
      }
    }
  }
}

// Fused EdgeConv on dst-sorted edges. Epilogue: segmented max per column
// (edges sorted by dst => ~2-3 segments per 64-edge tile), then atomicMax.
__global__ __launch_bounds__(256, 2) void k_edgeconv(
    const float* __restrict__ x, const float* __restrict__ ea,
    const int* __restrict__ src_s, const int* __restrict__ dst_s,
    const int* __restrict__ perm_s,
    const unsigned short* __restrict__ W1p, const float* __restrict__ b1,
    const unsigned short* __restrict__ W2p, const float* __restrict__ b2,
    float* __restrict__ h2, int E) {
  constexpr int KP1 = 200;  // 192 + 8 pad
  constexpr int KP2 = 264;  // 256 + 8 pad
  __shared__ unsigned short s_in[64 * KP1];
  __shared__ unsigned short s_hid[64 * KP2];
  __shared__ int s_src[64], s_dst[64], s_perm[64];
  const int tid = threadIdx.x;
  const int e0 = blockIdx.x * 64;
  if (tid < 64) {
    int e = e0 + tid;
    s_src[tid] = (e < E) ? src_s[e] : 0;
    s_dst[tid] = (e < E) ? dst_s[e] : 0;
    s_perm[tid] = (e < E) ? perm_s[e] : 0;
  }
  __syncthreads();
#pragma unroll
  for (int seg = 0; seg < 3; ++seg) {
#pragma unroll
    for (int it = 0; it < 4; ++it) {
      int idx = it * 256 + tid;
      int ei = idx >> 4;
      int c4 = (idx & 15) * 4;
      const float* row;
      if (seg == 0) row = x + (size_t)s_dst[ei] * 64;
      else if (seg == 1) row = x + (size_t)s_src[ei] * 64;
      else row = ea + (size_t)s_perm[ei] * 64;
      float4 v = make_float4(0.f, 0.f, 0.f, 0.f);
      if (e0 + ei < E) v = *(const float4*)(row + c4);
      ushort4 b;
      b.x = f2bf(v.x); b.y = f2bf(v.y); b.z = f2bf(v.z); b.w = f2bf(v.w);
      *(ushort4*)&s_in[ei * KP1 + seg * 64 + c4] = b;
    }
  }
  __syncthreads();

  const int lane = tid & 63, wid = tid >> 6;
  const int lr = lane & 15, lg = lane >> 4;
  f32x4 acc[4][4];
#pragma unroll
  for (int m = 0; m < 4; ++m)
#pragma unroll
    for (int n2 = 0; n2 < 4; ++n2) acc[m][n2] = zero4();

  // GEMM1: K=192 -> hidden 256
#pragma unroll
  for (int kt = 0; kt < 6; ++kt) {
    bf16x8 a[4];
#pragma unroll
    for (int m = 0; m < 4; ++m)
      a[m] = load_frag_split(&s_in[(m * 16 + lr) * KP1 + kt * 32 + lg * 4]);
#pragma unroll
    for (int n2 = 0; n2 < 4; ++n2) {
      int nt = wid * 4 + n2;
      bf16x8 b = *(const bf16x8*)&W1p[(((size_t)kt * 16 + nt) * 64 + lane) * 8];
#pragma unroll
      for (int m = 0; m < 4; ++m)
        acc[m][n2] = __builtin_amdgcn_mfma_f32_16x16x32_bf16(a[m], b, acc[m][n2], 0, 0, 0);
    }
  }
#pragma unroll
  for (int n2 = 0; n2 < 4; ++n2) {
    int col = (wid * 4 + n2) * 16 + lr;
    float bv = b1[col];
#pragma unroll
    for (int m = 0; m < 4; ++m)
#pragma unroll
      for (int r = 0; r < 4; ++r) {
        float v = fmaxf(acc[m][n2][r] + bv, 0.f);
        s_hid[(m * 16 + lg * 4 + r) * KP2 + col] = f2bf(v);
      }
  }
  __syncthreads();

  // GEMM2: K=256 -> out 256
#pragma unroll
  for (int m = 0; m < 4; ++m)
#pragma unroll
    for (int n2 = 0; n2 < 4; ++n2) acc[m][n2] = zero4();
#pragma unroll
  for (int kt = 0; kt < 8; ++kt) {
    bf16x8 a[4];
#pragma unroll
    for (int m = 0; m < 4; ++m)
      a[m] = load_frag_split(&s_hid[(m * 16 + lr) * KP2 + kt * 32 + lg * 4]);
#pragma unroll
    for (int n2 = 0; n2 < 4; ++n2) {
      int nt = wid * 4 + n2;
      bf16x8 b = *(const bf16x8*)&W2p[(((size_t)kt * 16 + nt) * 64 + lane) * 8];
#pragma unroll
      for (int m = 0; m < 4; ++m)
        acc[m][n2] = __builtin_amdgcn_mfma_f32_16x16x32_bf16(a[m], b, acc[m][n2], 0, 0, 0);
    }
  }

  // Stage relu(C+bias) as bf16 back into s_hid (all GEMM2 reads are done).
  __syncthreads();
#pragma unroll
  for (int n2 = 0; n2 < 4; ++n2) {
    int col = (wid * 4 + n2) * 16 + lr;
    float bv = b2[col];
#pragma unroll
    for (int m = 0; m < 4; ++m)
#pragma unroll
      for (int r = 0; r < 4; ++r) {
        int row = m * 16 + lg * 4 + r;
        float v = (e0 + row < E) ? fmaxf(acc[m][n2][r] + bv, 0.f) : 0.f;
        s_hid[row * KP2 + col] = f2bf(v);
      }
  }
  __syncthreads();

  // Segmented max scan: thread = column; rows sorted by dst.
  {
    const int col = tid;
    float run = 0.f;
    int cur = s_dst[0];
    for (int r = 0; r < 64; ++r) {
      int d2 = s_dst[r];
      if (d2 != cur) {
        if (run > 0.f)
          atomicMax((int*)&h2[(size_t)cur * 512 + 256 + col], __float_as_int(run));
        run = 0.f;
        cur = d2;
      }
      run = fmaxf(run, bf2f(s_hid[r * KP2 + col]));
    }
    if (run > 0.f)
      atomicMax((int*)&h2[(size_t)cur * 512 + 256 + col], __float_as_int(run));
  }
}

// Head MLP: wave-per-node, weights (except W2) staged in LDS.
__global__ __launch_bounds__(256) void k_head(
    const float* __restrict__ x, const float* __restrict__ out3,
    const float* __restrict__ W1, const float* __restrict__ b1,
    const float* __restrict__ W2, const float* __restrict__ b2,
    const float* __restrict__ W3, const float* __restrict__ b3,
    const float* __restrict__ W4, const float* __restrict__ b4,
    float* __restrict__ out, int n) {
  __shared__ float sW1[128 * 64];
  __shared__ float sW3[128 * 32];
  __shared__ float sW4[32 * 2];
  __shared__ float sb1[64], sb2[128], sb3[32], sb4[2];
  __shared__ float sbuf[4][352];
  const int tid = threadIdx.x;
  for (int i = tid; i < 128 * 64; i += 256) sW1[i] = W1[i];
  for (int i = tid; i < 128 * 32; i += 256) sW3[i] = W3[i];
  if (tid < 64) sW4[tid] = W4[tid];
  if (tid < 64) sb1[tid] = b1[tid];
  if (tid < 128) sb2[tid] = b2[tid];
  if (tid < 32) sb3[tid] = b3[tid];
  if (tid < 2) sb4[tid] = b4[tid];
  __syncthreads();
  const int wid = tid >> 6, lane = tid & 63;
  float* B = sbuf[wid];
  const int per = gridDim.x * 4;
  const int iters = (n + per - 1) / per;
  for (int it = 0; it < iters; ++it) {
    const int node = it * per + blockIdx.x * 4 + wid;
    const bool act = node < n;
    if (act) {
      B[lane] = x[(size_t)node * 64 + lane];
      B[64 + lane] = out3[(size_t)node * 64 + lane];
    }
    __syncthreads();
    if (act) {
      float o = sb1[lane];
#pragma unroll 8
      for (int k = 0; k < 128; ++k) o += B[k] * sW1[k * 64 + lane];
      B[128 + lane] = softplusf(o);
    }
    __syncthreads();
    if (act) {
      float o0 = sb2[lane], o1 = sb2[64 + lane];
#pragma unroll 8
      for (int k = 0; k < 64; ++k) {
        float v = B[128 + k];
        o0 += v * W2[k * 128 + lane];
        o1 += v * W2[k * 128 + 64 + lane];
      }
      B[192 + lane] = softplusf(o0);
      B[256 + lane] = softplusf(o1);
    }
    __syncthreads();
    if (act && lane < 32) {
      float o = sb3[lane];
#pragma unroll 8
      for (int k = 0; k < 128; ++k) o += B[192 + k] * sW3[k * 32 + lane];
      B[320 + lane] = softplusf(o);
    }
    __syncthreads();
    if (act && lane < 2) {
      float o = sb4[lane];
#pragma unroll
      for (int k = 0; k < 32; ++k) o += B[320 + k] * sW4[k * 2 + lane];
      out[(size_t)lane * n + node] = o;
    }
    __syncthreads();
  }
}

static inline size_t alignup(size_t v) { return (v + 255) & ~(size_t)255; }

extern "C" void kernel_launch(void* const* d_in, const int* in_sizes, int n_in,
                              void* d_out, int out_size, void* d_ws, size_t ws_size,
                              hipStream_t stream) {
  const float* x = (const float*)d_in[0];
  const int* ei = (const int*)d_in[1];
  const float* ea = (const float*)d_in[2];
  const float* c1W = (const float*)d_in[3];
  const float* c1b = (const float*)d_in[4];
  const float* eW1 = (const float*)d_in[5];
  const float* eb1 = (const float*)d_in[6];
  const float* eW2 = (const float*)d_in[7];
  const float* eb2 = (const float*)d_in[8];
  const float* c2W = (const float*)d_in[9];
  const float* c2b = (const float*)d_in[10];
  const float* c3W = (const float*)d_in[11];
  const float* c3b = (const float*)d_in[12];
  const float* l1W = (const float*)d_in[13];
  const float* l1b = (const float*)d_in[14];
  const float* l2W = (const float*)d_in[15];
  const float* l2b = (const float*)d_in[16];
  const float* l3W = (const float*)d_in[17];
  const float* l3b = (const float*)d_in[18];
  const float* l4W = (const float*)d_in[19];
  const float* l4b = (const float*)d_in[20];
  const int n = in_sizes[0] / 64;
  const int E = in_sizes[1] / 2;
  const int* srcs = ei;
  const int* dsts = ei + E;

  char* w = (char*)d_ws;
  auto alloc = [&](size_t bytes) {
    char* p = w;
    w += alignup(bytes);
    return p;
  };
  float* dis = (float*)alloc((size_t)n * 4);
  int* degi = (int*)alloc((size_t)n * 4);
  int* ptr = (int*)alloc((size_t)(n + 1) * 4);
  int* fillc = (int*)alloc((size_t)n * 4);
  int* src_s = (int*)alloc((size_t)E * 4);
  int* dst_s = (int*)alloc((size_t)E * 4);
  int* perm_s = (int*)alloc((size_t)E * 4);
  float* agg1 = (float*)alloc((size_t)n * 64 * 4);
  float* h2 = (float*)alloc((size_t)n * 512 * 4);  // [out1 | out_e1]
  float* hw2 = (float*)alloc((size_t)n * 256 * 4);
  float* out2 = (float*)alloc((size_t)n * 256 * 4);
  float* hw3 = (float*)alloc((size_t)n * 64 * 4);
  float* out3 = (float*)alloc((size_t)n * 64 * 4);
  unsigned short* p_c1 = (unsigned short*)alloc(64 * 256 * 2);
  unsigned short* p_e1 = (unsigned short*)alloc(192 * 256 * 2);
  unsigned short* p_e2 = (unsigned short*)alloc(256 * 256 * 2);
  unsigned short* p_c2 = (unsigned short*)alloc(512 * 256 * 2);
  unsigned short* p_c3 = (unsigned short*)alloc(256 * 64 * 2);

  hipMemsetAsync(degi, 0, (size_t)n * 4, stream);
  hipMemsetAsync(fillc, 0, (size_t)n * 4, stream);
  hipMemsetAsync(h2, 0, (size_t)n * 512 * 4, stream);

  pack_weight<<<(64 * 256) / 256, 256, 0, stream>>>(c1W, p_c1, 64, 256);
  pack_weight<<<(192 * 256) / 256, 256, 0, stream>>>(eW1, p_e1, 192, 256);
  pack_weight<<<(256 * 256) / 256, 256, 0, stream>>>(eW2, p_e2, 256, 256);
  pack_weight<<<(512 * 256) / 256, 256, 0, stream>>>(c2W, p_c2, 512, 256);
  pack_weight<<<(256 * 64) / 256, 256, 0, stream>>>(c3W, p_c3, 256, 64);

  // CSR build
  k_deg<<<(E + 255) / 256, 256, 0, stream>>>(dsts, degi, E);
  k_dis<<<(n + 255) / 256, 256, 0, stream>>>(degi, dis, n);
  k_scan<<<1, 1024, 0, stream>>>(degi, ptr, n);
  k_fill<<<(E + 255) / 256, 256, 0, stream>>>(srcs, dsts, ptr, fillc,
                                              src_s, dst_s, perm_s, E);

  const int ablocks = (n + 3) / 4;
  const int gblocks = (n + 63) / 64;

  // conv1: gather-aggregate x (64 ch), then GEMM with fused self-loop term
  k_gather_agg<64, false><<<ablocks, 256, 0, stream>>>(x, src_s, ptr, dis,
                                                       nullptr, nullptr, agg1, n);
  gcn_gemm<64, 256, true, true><<<gblocks, 256, 0, stream>>>(agg1, x, dis, p_c1, c1b, h2, 512, n);

  // EdgeConv -> h2[:, 256:512] (sorted edges, segmented-max epilogue)
  k_edgeconv<<<(E + 63) / 64, 256, 0, stream>>>(x, ea, src_s, dst_s, perm_s,
                                                p_e1, eb1, p_e2, eb2, h2, E);

  // conv2: matmul then gather-aggregate (256 ch) with fused finalize
  gcn_gemm<512, 256, false, false><<<gblocks, 256, 0, stream>>>(h2, nullptr, nullptr, p_c2, nullptr, hw2, 256, n);
  k_gather_agg<256, true><<<ablocks, 256, 0, stream>>>(hw2, src_s, ptr, dis,
                                                       hw2, c2b, out2, n);

  // conv3: matmul then gather-aggregate (64 ch) with fused finalize
  gcn_gemm<256, 64, false, false><<<gblocks, 256, 0, stream>>>(out2, nullptr, nullptr, p_c3, nullptr, hw3, 64, n);
  k_gather_agg<64, true><<<ablocks, 256, 0, stream>>>(hw3, src_s, ptr, dis,
                                                      hw3, c3b, out3, n);

  k_head<<<320, 256, 0, stream>>>(x, out3, l1W, l1b, l2W, l2b, l3W, l3b, l4W, l4b,
                                  (float*)d_out, n);
}